// Round 1
// baseline (1278.297 us; speedup 1.0000x reference)
//
#include <hip/hip_runtime.h>

#define NX 352
#define NY 256
#define NZ 64

__device__ __forceinline__ float limiter(float cr) {
    return fmaxf(0.f, fmaxf(fminf(1.f, 2.f * cr), fminf(2.f, cr)));
}

// ---------------- Kernel A: tridiag solve + surface corr + horizontal diffusion ----------
__global__ void kA(const float* __restrict__ tke, const float* __restrict__ kappaM,
                   const float* __restrict__ mxl, const float* __restrict__ forc,
                   const float* __restrict__ forc_surf, const int* __restrict__ kbot,
                   const float* __restrict__ maskU, const float* __restrict__ maskV,
                   const float* __restrict__ maskW,
                   const float* __restrict__ dxt, const float* __restrict__ dxu,
                   const float* __restrict__ dyt, const float* __restrict__ dyu,
                   const float* __restrict__ dzt, const float* __restrict__ dzw,
                   const float* __restrict__ cost, const float* __restrict__ cosu,
                   float* __restrict__ out_tke, float* __restrict__ out_corr)
{
    int c = blockIdx.x * blockDim.x + threadIdx.x;
    if (c >= NX * NY) return;
    int i = c / NY, j = c % NY;
    size_t ij = (size_t)i * NY + j;
    size_t base1 = ij * NZ;       // (X,Y,Z) arrays
    size_t base3 = base1 * 3;     // (X,Y,Z,3) arrays

    bool interior = (i >= 2 && i < NX - 2 && j >= 2 && j < NY - 2);
    if (!interior) {
        #pragma unroll 1
        for (int k = 0; k < NZ; k++)
            out_tke[base3 + k * 3 + 1] = tke[base3 + k * 3 + 1];
        out_corr[ij] = 0.f;
        return;
    }

    int ks = kbot[ij] - 1;
    bool land = (ks >= 0);
    float dzw_last_half = 0.5f * dzw[NZ - 1];

    float cp[NZ], dp[NZ];
    float delta_m1 = 0.f;
    float cpk = 0.f, dpk = 0.f;

    #pragma unroll 1
    for (int k = 0; k < NZ; k++) {
        float kap = kappaM[base1 + k];
        float delta_k = (k < NZ - 1) ? 0.5f * (kap + kappaM[base1 + k + 1]) / dzt[k + 1] : 0.f;
        float tkv = tke[base3 + k * 3 + 0];
        float sqrttke = sqrtf(fmaxf(0.f, tkv));
        float mx = mxl[base1 + k];
        float diss = 0.7f * sqrttke / mx;

        float a, b;
        if (k == 0)           { a = 0.f; b = 0.f; }
        else if (k < NZ - 1)  { a = -delta_m1 / dzw[k];
                                b = 1.f + (delta_k + delta_m1) / dzw[k] + diss; }
        else                  { a = -delta_m1 / dzw_last_half;
                                b = 1.f + delta_m1 / dzw_last_half + diss; }
        float b_edge = 1.f + delta_k / dzw[k] + diss;
        float c_ = (k < NZ - 1) ? -delta_k / dzw[k] : 0.f;
        float d_ = tkv + forc[base1 + k];
        if (k == NZ - 1) d_ += forc_surf[ij] / dzw_last_half;

        bool water = land && (k >= ks);
        bool edge  = land && (k == ks);
        float A = (water && !edge) ? a : 0.f;
        float B = edge ? b_edge : (water ? b : 1.f);
        float C = water ? c_ : 0.f;
        float D = water ? d_ : 0.f;

        float denom = B - A * cpk;
        cpk = C / denom;
        dpk = (D - A * dpk) / denom;
        cp[k] = cpk; dp[k] = dpk;
        delta_m1 = delta_k;
    }

    float cj = cost[j];
    float inv_cj_dxt = 1.f / (cj * dxt[i]);
    float inv_cj_dyt = 1.f / (cj * dyt[j]);
    float inv_dxu_i  = 1.f / (cj * dxu[i]);
    float inv_dxu_im = 1.f / (cj * dxu[i - 1]);
    float fn_j_fac  = cosu[j] / dyu[j];
    float fn_jm_fac = cosu[j - 1] / dyu[j - 1];
    float surf_corr = 0.f;
    float xnext = 0.f;

    #pragma unroll 1
    for (int k = NZ - 1; k >= 0; k--) {
        xnext = dp[k] - cp[k] * xnext;
        bool water = land && (k >= ks);
        float val = water ? xnext : tke[base3 + k * 3 + 1];

        if (k == NZ - 1) {
            if (val < 0.f) { surf_corr = -val * dzw_last_half; val = 0.f; }
        }

        // horizontal diffusion on tke tau
        size_t o  = base3 + k * 3;
        float tc   = tke[o];
        float te   = tke[o + (size_t)NY * NZ * 3];
        float tw   = tke[o - (size_t)NY * NZ * 3];
        float tn   = tke[o + (size_t)NZ * 3];
        float ts   = tke[o - (size_t)NZ * 3];
        float fe1 = 2000.f * (te - tc) * inv_dxu_i  * maskU[base1 + k];
        float fe0 = 2000.f * (tc - tw) * inv_dxu_im * maskU[base1 - (size_t)NY * NZ + k];
        float fn1 = 2000.f * (tn - tc) * fn_j_fac   * maskV[base1 + k];
        float fn0 = 2000.f * (tc - ts) * fn_jm_fac  * maskV[base1 - NZ + k];
        val += maskW[base1 + k] * ((fe1 - fe0) * inv_cj_dxt + (fn1 - fn0) * inv_cj_dyt);

        out_tke[base3 + k * 3 + 1] = val;
    }
    out_corr[ij] = surf_corr;
}

// ---------------- Kernel B: superbee advection -> dtke tau, AB update, copies ----------
__device__ __forceinline__ float adv_x(const float* __restrict__ tke,
                                       const float* __restrict__ maskW,
                                       const float* __restrict__ u,
                                       int ii, int j, int k, float cj,
                                       const float* __restrict__ dxt)
{
    size_t col = ((size_t)ii * NY + j) * NZ + k;
    const size_t sx = (size_t)NY * NZ;
    float vim1 = tke[(col - sx) * 3];
    float vi   = tke[col * 3];
    float vip1 = tke[(col + sx) * 3];
    float vip2 = tke[(col + 2 * sx) * 3];
    float m_im1 = maskW[col] * maskW[col - sx];                 // maskUtr[ii-1]
    float m_i   = maskW[col + sx] * maskW[col];                 // maskUtr[ii]
    float m_ip1 = (ii + 1 < NX - 1) ? maskW[col + 2 * sx] * maskW[col + sx] : 0.f;
    float vel = u[col * 3];
    float rjp = (vip2 - vip1) * m_ip1;
    float rj  = (vip1 - vi) * m_i;
    float rjm = (vi - vim1) * m_im1;
    float uCFL = fabsf(vel / (cj * dxt[ii]));
    float rden = (fabsf(rj) < 1e-20f) ? 1e-20f : rj;
    float cr = limiter(((vel > 0.f) ? rjm : rjp) / rden);
    return vel * (vip1 + vi) * 0.5f - fabsf(vel) * ((1.f - cr) + uCFL * cr) * rj * 0.5f;
}

__device__ __forceinline__ float adv_y(const float* __restrict__ tke,
                                       const float* __restrict__ maskW,
                                       const float* __restrict__ v,
                                       int i, int jj, int k,
                                       const float* __restrict__ dyt,
                                       const float* __restrict__ cost,
                                       const float* __restrict__ cosu)
{
    size_t col = ((size_t)i * NY + jj) * NZ + k;
    const size_t sy = (size_t)NZ;
    float vjm1 = tke[(col - sy) * 3];
    float vj   = tke[col * 3];
    float vjp1 = tke[(col + sy) * 3];
    float vjp2 = tke[(col + 2 * sy) * 3];
    float m_jm1 = maskW[col] * maskW[col - sy];
    float m_j   = maskW[col + sy] * maskW[col];
    float m_jp1 = (jj + 1 < NY - 1) ? maskW[col + 2 * sy] * maskW[col + sy] : 0.f;
    float vel = v[col * 3];
    float vf  = cosu[jj];
    float rjp = (vjp2 - vjp1) * m_jp1;
    float rj  = (vjp1 - vj) * m_j;
    float rjm = (vj - vjm1) * m_jm1;
    float uCFL = fabsf(vf * vel / (cost[jj] * dyt[jj]));
    float rden = (fabsf(rj) < 1e-20f) ? 1e-20f : rj;
    float cr = limiter(((vel > 0.f) ? rjm : rjp) / rden);
    return vf * vel * (vjp1 + vj) * 0.5f - fabsf(vf * vel) * ((1.f - cr) + uCFL * cr) * rj * 0.5f;
}

__device__ __forceinline__ float adv_z(const float* __restrict__ tke,
                                       const float* __restrict__ maskW,
                                       const float* __restrict__ w,
                                       size_t base1, int kk,
                                       const float* __restrict__ dzw)
{
    size_t base3 = base1 * 3;
    float vkm1 = (kk - 1 >= 0) ? tke[base3 + (kk - 1) * 3] : 0.f;
    float vk   = tke[base3 + kk * 3];
    float vkp1 = tke[base3 + (kk + 1) * 3];
    float vkp2 = (kk + 2 < NZ) ? tke[base3 + (kk + 2) * 3] : 0.f;
    float m_km1 = (kk - 1 >= 0) ? maskW[base1 + kk] * maskW[base1 + kk - 1] : 0.f;
    float m_k   = maskW[base1 + kk + 1] * maskW[base1 + kk];
    float m_kp1 = (kk + 1 < NZ - 1) ? maskW[base1 + kk + 2] * maskW[base1 + kk + 1] : 0.f;
    float vel = w[base3 + kk * 3];
    float rjp = (vkp2 - vkp1) * m_kp1;
    float rj  = (vkp1 - vk) * m_k;
    float rjm = (vk - vkm1) * m_km1;
    float uCFL = fabsf(vel / dzw[kk]);
    float rden = (fabsf(rj) < 1e-20f) ? 1e-20f : rj;
    float cr = limiter(((vel > 0.f) ? rjm : rjp) / rden);
    return vel * (vkp1 + vk) * 0.5f - fabsf(vel) * ((1.f - cr) + uCFL * cr) * rj * 0.5f;
}

__global__ void kB(const float* __restrict__ tke, const float* __restrict__ dtke,
                   const float* __restrict__ u, const float* __restrict__ v,
                   const float* __restrict__ w, const float* __restrict__ maskW,
                   const float* __restrict__ dxt, const float* __restrict__ dyt,
                   const float* __restrict__ dzw,
                   const float* __restrict__ cost, const float* __restrict__ cosu,
                   float* __restrict__ out_tke, float* __restrict__ out_dtke)
{
    int k = threadIdx.x;                       // 0..63
    int j = blockIdx.x * blockDim.y + threadIdx.y;
    int i = blockIdx.y;
    size_t idx1 = ((size_t)i * NY + j) * NZ + k;
    size_t idx3 = idx1 * 3;
    size_t base1 = ((size_t)i * NY + j) * NZ;

    // copy unchanged slices
    float t2  = tke[idx3 + 2];
    out_tke[idx3 + 0]  = tke[idx3 + 0];
    out_tke[idx3 + 2]  = t2;
    float d2 = dtke[idx3 + 2];
    out_dtke[idx3 + 1] = dtke[idx3 + 1];
    out_dtke[idx3 + 2] = d2;

    bool interior = (i >= 2 && i < NX - 2 && j >= 2 && j < NY - 2);
    float dtke_tau;
    if (interior) {
        float cj = cost[j];
        float fe1 = adv_x(tke, maskW, u, i,     j, k, cj, dxt);
        float fe0 = adv_x(tke, maskW, u, i - 1, j, k, cj, dxt);
        float fn1 = adv_y(tke, maskW, v, i, j,     k, dyt, cost, cosu);
        float fn0 = adv_y(tke, maskW, v, i, j - 1, k, dyt, cost, cosu);
        float hor = maskW[idx1] * (-(fe1 - fe0) / (cj * dxt[i])
                                   - (fn1 - fn0) / (cj * dyt[j]));
        float ftk   = (k < NZ - 1) ? adv_z(tke, maskW, w, base1, k,     dzw) : 0.f;
        float ftkm1 = (k > 0)      ? adv_z(tke, maskW, w, base1, k - 1, dzw) : 0.f;
        float vert;
        if (k == 0)           vert = -ftk / dzw[0];
        else if (k < NZ - 1)  vert = -(ftk - ftkm1) / dzw[k];
        else                  vert = ftkm1 / (0.5f * dzw[NZ - 1]);
        dtke_tau = hor + vert;
    } else {
        dtke_tau = dtke[idx3 + 0];
    }
    out_dtke[idx3 + 0] = dtke_tau;

    // Adams-Bashforth update of taup1 (kernel A wrote the partial value)
    float partial = out_tke[idx3 + 1];
    out_tke[idx3 + 1] = partial + 1.6f * dtke_tau - 0.6f * d2;
}

extern "C" void kernel_launch(void* const* d_in, const int* in_sizes, int n_in,
                              void* d_out, int out_size, void* d_ws, size_t ws_size,
                              hipStream_t stream)
{
    const float* u         = (const float*)d_in[0];
    const float* v         = (const float*)d_in[1];
    const float* w         = (const float*)d_in[2];
    const float* maskU     = (const float*)d_in[3];
    const float* maskV     = (const float*)d_in[4];
    const float* maskW     = (const float*)d_in[5];
    const float* dxt       = (const float*)d_in[6];
    const float* dxu       = (const float*)d_in[7];
    const float* dyt       = (const float*)d_in[8];
    const float* dyu       = (const float*)d_in[9];
    const float* dzt       = (const float*)d_in[10];
    const float* dzw       = (const float*)d_in[11];
    const float* cost      = (const float*)d_in[12];
    const float* cosu      = (const float*)d_in[13];
    const int*   kbot      = (const int*)d_in[14];
    const float* kappaM    = (const float*)d_in[15];
    const float* mxl       = (const float*)d_in[16];
    const float* forc      = (const float*)d_in[17];
    const float* forc_surf = (const float*)d_in[18];
    const float* tke       = (const float*)d_in[19];
    const float* dtke      = (const float*)d_in[20];

    float* out_tke  = (float*)d_out;
    float* out_dtke = out_tke + (size_t)NX * NY * NZ * 3;
    float* out_corr = out_dtke + (size_t)NX * NY * NZ * 3;

    kA<<<dim3((NX * NY + 255) / 256), dim3(256), 0, stream>>>(
        tke, kappaM, mxl, forc, forc_surf, kbot, maskU, maskV, maskW,
        dxt, dxu, dyt, dyu, dzt, dzw, cost, cosu, out_tke, out_corr);

    kB<<<dim3(NY / 4, NX), dim3(64, 4), 0, stream>>>(
        tke, dtke, u, v, w, maskW, dxt, dyt, dzw, cost, cosu,
        out_tke, out_dtke);
}

// Round 2
// 268.778 us; speedup vs baseline: 4.7560x; 4.7560x over previous
//
#include <hip/hip_runtime.h>

#define NX 352
#define NY 256
#define NZ 64

__device__ __forceinline__ float limiter(float cr) {
    return fmaxf(0.f, fmaxf(fminf(1.f, 2.f * cr), fminf(2.f, cr)));
}

__device__ __forceinline__ float adv_x(const float* __restrict__ tke,
                                       const float* __restrict__ maskW,
                                       const float* __restrict__ u,
                                       int ii, int j, int k, float cj,
                                       const float* __restrict__ dxt)
{
    size_t col = ((size_t)ii * NY + j) * NZ + k;
    const size_t sx = (size_t)NY * NZ;
    float vim1 = tke[(col - sx) * 3];
    float vi   = tke[col * 3];
    float vip1 = tke[(col + sx) * 3];
    float vip2 = tke[(col + 2 * sx) * 3];
    float m_im1 = maskW[col] * maskW[col - sx];
    float m_i   = maskW[col + sx] * maskW[col];
    float m_ip1 = (ii + 1 < NX - 1) ? maskW[col + 2 * sx] * maskW[col + sx] : 0.f;
    float vel = u[col * 3];
    float rjp = (vip2 - vip1) * m_ip1;
    float rj  = (vip1 - vi) * m_i;
    float rjm = (vi - vim1) * m_im1;
    float uCFL = fabsf(vel / (cj * dxt[ii]));
    float rden = (fabsf(rj) < 1e-20f) ? 1e-20f : rj;
    float cr = limiter(((vel > 0.f) ? rjm : rjp) / rden);
    return vel * (vip1 + vi) * 0.5f - fabsf(vel) * ((1.f - cr) + uCFL * cr) * rj * 0.5f;
}

__device__ __forceinline__ float adv_y(const float* __restrict__ tke,
                                       const float* __restrict__ maskW,
                                       const float* __restrict__ v,
                                       int i, int jj, int k,
                                       const float* __restrict__ dyt,
                                       const float* __restrict__ cost,
                                       const float* __restrict__ cosu)
{
    size_t col = ((size_t)i * NY + jj) * NZ + k;
    const size_t sy = (size_t)NZ;
    float vjm1 = tke[(col - sy) * 3];
    float vj   = tke[col * 3];
    float vjp1 = tke[(col + sy) * 3];
    float vjp2 = tke[(col + 2 * sy) * 3];
    float m_jm1 = maskW[col] * maskW[col - sy];
    float m_j   = maskW[col + sy] * maskW[col];
    float m_jp1 = (jj + 1 < NY - 1) ? maskW[col + 2 * sy] * maskW[col + sy] : 0.f;
    float vel = v[col * 3];
    float vf  = cosu[jj];
    float rjp = (vjp2 - vjp1) * m_jp1;
    float rj  = (vjp1 - vj) * m_j;
    float rjm = (vj - vjm1) * m_jm1;
    float uCFL = fabsf(vf * vel / (cost[jj] * dyt[jj]));
    float rden = (fabsf(rj) < 1e-20f) ? 1e-20f : rj;
    float cr = limiter(((vel > 0.f) ? rjm : rjp) / rden);
    return vf * vel * (vjp1 + vj) * 0.5f - fabsf(vf * vel) * ((1.f - cr) + uCFL * cr) * rj * 0.5f;
}

__device__ __forceinline__ float adv_z(const float* __restrict__ tke,
                                       const float* __restrict__ maskW,
                                       const float* __restrict__ w,
                                       size_t base1, int kk,
                                       const float* __restrict__ dzw)
{
    size_t base3 = base1 * 3;
    float vkm1 = (kk - 1 >= 0) ? tke[base3 + (kk - 1) * 3] : 0.f;
    float vk   = tke[base3 + kk * 3];
    float vkp1 = tke[base3 + (kk + 1) * 3];
    float vkp2 = (kk + 2 < NZ) ? tke[base3 + (kk + 2) * 3] : 0.f;
    float m_km1 = (kk - 1 >= 0) ? maskW[base1 + kk] * maskW[base1 + kk - 1] : 0.f;
    float m_k   = maskW[base1 + kk + 1] * maskW[base1 + kk];
    float m_kp1 = (kk + 1 < NZ - 1) ? maskW[base1 + kk + 2] * maskW[base1 + kk + 1] : 0.f;
    float vel = w[base3 + kk * 3];
    float rjp = (vkp2 - vkp1) * m_kp1;
    float rj  = (vkp1 - vk) * m_k;
    float rjm = (vk - vkm1) * m_km1;
    float uCFL = fabsf(vel / dzw[kk]);
    float rden = (fabsf(rj) < 1e-20f) ? 1e-20f : rj;
    float cr = limiter(((vel > 0.f) ? rjm : rjp) / rden);
    return vel * (vkp1 + vk) * 0.5f - fabsf(vel) * ((1.f - cr) + uCFL * cr) * rj * 0.5f;
}

// One fused kernel: wave per column (lane = k). PCR tridiag solve, then
// diffusion + superbee advection + Adams-Bashforth, all coalesced along k.
__global__ __launch_bounds__(256) void
tke_fused(const float* __restrict__ tke, const float* __restrict__ dtke,
          const float* __restrict__ u, const float* __restrict__ v,
          const float* __restrict__ w,
          const float* __restrict__ maskU, const float* __restrict__ maskV,
          const float* __restrict__ maskW,
          const float* __restrict__ kappaM, const float* __restrict__ mxl,
          const float* __restrict__ forc, const float* __restrict__ forc_surf,
          const int* __restrict__ kbot,
          const float* __restrict__ dxt, const float* __restrict__ dxu,
          const float* __restrict__ dyt, const float* __restrict__ dyu,
          const float* __restrict__ dzt, const float* __restrict__ dzw,
          const float* __restrict__ cost, const float* __restrict__ cosu,
          float* __restrict__ out_tke, float* __restrict__ out_dtke,
          float* __restrict__ out_corr)
{
    const int lane = threadIdx.x;                       // k index, 0..63
    const int col  = blockIdx.x * blockDim.y + threadIdx.y;
    const int i = col / NY, j = col % NY;
    const size_t base1 = (size_t)col * NZ;
    const size_t idx1  = base1 + lane;
    const size_t idx3  = idx1 * 3;
    const bool interior = (i >= 2 && i < NX - 2 && j >= 2 && j < NY - 2);

    // column-local input values
    const float tk_tau = tke[idx3 + 0];
    const float tk_tp1 = tke[idx3 + 1];
    const float tk_tm1 = tke[idx3 + 2];
    const float d_tm1  = dtke[idx3 + 2];

    // pass-through slices
    out_tke[idx3 + 0]  = tk_tau;
    out_tke[idx3 + 2]  = tk_tm1;
    out_dtke[idx3 + 1] = dtke[idx3 + 1];
    out_dtke[idx3 + 2] = d_tm1;

    // ---------- tridiagonal system setup (lane = row k) ----------
    const float dzwk     = dzw[lane];
    const float dzw_last = 0.5f * dzw[NZ - 1];

    float kap   = kappaM[idx1];
    float kap_p = __shfl_down(kap, 1);
    float dzt_p = dzt[(lane < NZ - 1) ? lane + 1 : NZ - 1];
    float delta = (lane < NZ - 1) ? 0.5f * (kap + kap_p) / dzt_p : 0.f;
    float delta_m = __shfl_up(delta, 1);
    if (lane == 0) delta_m = 0.f;

    float diss = 0.7f * sqrtf(fmaxf(0.f, tk_tau)) / mxl[idx1];

    float a, b;
    if (lane == 0)            { a = 0.f; b = 0.f; }
    else if (lane < NZ - 1)   { a = -delta_m / dzwk;
                                b = 1.f + (delta + delta_m) / dzwk + diss; }
    else                      { a = -delta_m / dzw_last;
                                b = 1.f + delta_m / dzw_last + diss; }
    const float b_edge = 1.f + delta / dzwk + diss;
    const float c = (lane < NZ - 1) ? -delta / dzwk : 0.f;
    float d = tk_tau + forc[idx1];
    if (lane == NZ - 1) d += forc_surf[col] / dzw_last;

    const int  ks    = kbot[col] - 1;
    const bool land  = interior && (ks >= 0);
    const bool water = land && (lane >= ks);
    const bool edge  = land && (lane == ks);

    float A = (water && !edge) ? a : 0.f;
    float B = edge ? b_edge : (water ? b : 1.f);
    float C = water ? c : 0.f;
    float D = water ? d : 0.f;

    // ---------- parallel cyclic reduction (6 steps) ----------
    #pragma unroll
    for (int s = 1; s < NZ; s <<= 1) {
        float am = __shfl_up(A, s), bm = __shfl_up(B, s);
        float cm = __shfl_up(C, s), dm = __shfl_up(D, s);
        if (lane < s) { am = 0.f; bm = 1.f; cm = 0.f; dm = 0.f; }
        float ap = __shfl_down(A, s), bp = __shfl_down(B, s);
        float cq = __shfl_down(C, s), dq = __shfl_down(D, s);
        if (lane + s >= NZ) { ap = 0.f; bp = 1.f; cq = 0.f; dq = 0.f; }
        float alpha = -A / bm;
        float beta  = -C / bp;
        float Bn = B + alpha * cm + beta * ap;
        float Dn = D + alpha * dm + beta * dq;
        A = alpha * am;
        C = beta * cq;
        B = Bn;
        D = Dn;
    }
    const float x = D / B;

    float partial = water ? x : tk_tp1;
    float corr = 0.f;
    if (lane == NZ - 1) {
        if (interior && partial < 0.f) { corr = -partial * dzw_last; partial = 0.f; }
        out_corr[col] = corr;
    }

    // ---------- diffusion + advection ----------
    float dtke_tau;
    float diff = 0.f;
    if (interior) {
        const float cj = cost[j];
        const size_t sx1 = (size_t)NY * NZ;

        // horizontal diffusion on tke tau
        float te = tke[(idx1 + sx1) * 3], tw = tke[(idx1 - sx1) * 3];
        float tn = tke[(idx1 + NZ) * 3],  ts = tke[(idx1 - NZ) * 3];
        float fe1 = 2000.f * (te - tk_tau) / (cj * dxu[i])     * maskU[idx1];
        float fe0 = 2000.f * (tk_tau - tw) / (cj * dxu[i - 1]) * maskU[idx1 - sx1];
        float fn1 = 2000.f * (tn - tk_tau) * (cosu[j]     / dyu[j])     * maskV[idx1];
        float fn0 = 2000.f * (tk_tau - ts) * (cosu[j - 1] / dyu[j - 1]) * maskV[idx1 - NZ];
        diff = maskW[idx1] * ((fe1 - fe0) / (cj * dxt[i]) + (fn1 - fn0) / (cj * dyt[j]));

        // superbee advection -> dtke tau
        float fe_1 = adv_x(tke, maskW, u, i,     j, lane, cj, dxt);
        float fe_0 = adv_x(tke, maskW, u, i - 1, j, lane, cj, dxt);
        float fn_1 = adv_y(tke, maskW, v, i, j,     lane, dyt, cost, cosu);
        float fn_0 = adv_y(tke, maskW, v, i, j - 1, lane, dyt, cost, cosu);
        float hor = maskW[idx1] * (-(fe_1 - fe_0) / (cj * dxt[i])
                                   - (fn_1 - fn_0) / (cj * dyt[j]));
        float ftk   = (lane < NZ - 1) ? adv_z(tke, maskW, w, base1, lane,     dzw) : 0.f;
        float ftkm1 = (lane > 0)      ? adv_z(tke, maskW, w, base1, lane - 1, dzw) : 0.f;
        float vert;
        if (lane == 0)           vert = -ftk / dzw[0];
        else if (lane < NZ - 1)  vert = -(ftk - ftkm1) / dzwk;
        else                     vert = ftkm1 / dzw_last;
        dtke_tau = hor + vert;
    } else {
        dtke_tau = dtke[idx3 + 0];
    }
    out_dtke[idx3 + 0] = dtke_tau;

    // Adams-Bashforth update of taup1
    out_tke[idx3 + 1] = partial + diff + 1.6f * dtke_tau - 0.6f * d_tm1;
}

extern "C" void kernel_launch(void* const* d_in, const int* in_sizes, int n_in,
                              void* d_out, int out_size, void* d_ws, size_t ws_size,
                              hipStream_t stream)
{
    const float* u         = (const float*)d_in[0];
    const float* v         = (const float*)d_in[1];
    const float* w         = (const float*)d_in[2];
    const float* maskU     = (const float*)d_in[3];
    const float* maskV     = (const float*)d_in[4];
    const float* maskW     = (const float*)d_in[5];
    const float* dxt       = (const float*)d_in[6];
    const float* dxu       = (const float*)d_in[7];
    const float* dyt       = (const float*)d_in[8];
    const float* dyu       = (const float*)d_in[9];
    const float* dzt       = (const float*)d_in[10];
    const float* dzw       = (const float*)d_in[11];
    const float* cost      = (const float*)d_in[12];
    const float* cosu      = (const float*)d_in[13];
    const int*   kbot      = (const int*)d_in[14];
    const float* kappaM    = (const float*)d_in[15];
    const float* mxl       = (const float*)d_in[16];
    const float* forc      = (const float*)d_in[17];
    const float* forc_surf = (const float*)d_in[18];
    const float* tke       = (const float*)d_in[19];
    const float* dtke      = (const float*)d_in[20];

    float* out_tke  = (float*)d_out;
    float* out_dtke = out_tke + (size_t)NX * NY * NZ * 3;
    float* out_corr = out_dtke + (size_t)NX * NY * NZ * 3;

    tke_fused<<<dim3((NX * NY) / 4), dim3(64, 4), 0, stream>>>(
        tke, dtke, u, v, w, maskU, maskV, maskW,
        kappaM, mxl, forc, forc_surf, kbot,
        dxt, dxu, dyt, dyu, dzt, dzw, cost, cosu,
        out_tke, out_dtke, out_corr);
}

// Round 3
// 187.054 us; speedup vs baseline: 6.8339x; 1.4369x over previous
//
#include <hip/hip_runtime.h>

#define NX 352
#define NY 256
#define NZ 64

__device__ __forceinline__ float rcpf(float x) { return __builtin_amdgcn_rcpf(x); }

__device__ __forceinline__ float limiter(float cr) {
    return fmaxf(0.f, fmaxf(fminf(1.f, 2.f * cr), fminf(2.f, cr)));
}

// superbee flux; cr-switch uses raw vel sign (reference semantics), uCFL uses velfac*vel
__device__ __forceinline__ float sbflux(float vm1, float v0, float vp1, float vp2,
                                        float mm1, float m0, float mp1,
                                        float vel, float velfac, float rinv_dx)
{
    float rjp = (vp2 - vp1) * mp1;
    float rj  = (vp1 - v0) * m0;
    float rjm = (v0 - vm1) * mm1;
    float fv = velfac * vel;
    float uCFL = fabsf(fv * rinv_dx);
    float rden = (fabsf(rj) < 1e-20f) ? 1e-20f : rj;
    float cr = limiter(((vel > 0.f) ? rjm : rjp) * rcpf(rden));
    return fv * (vp1 + v0) * 0.5f - fabsf(fv) * ((1.f - cr) + uCFL * cr) * rj * 0.5f;
}

__global__ __launch_bounds__(256) void
tke_fused(const float* __restrict__ tke, const float* __restrict__ dtke,
          const float* __restrict__ u, const float* __restrict__ v,
          const float* __restrict__ w,
          const float* __restrict__ maskU, const float* __restrict__ maskV,
          const float* __restrict__ maskW,
          const float* __restrict__ kappaM, const float* __restrict__ mxl,
          const float* __restrict__ forc, const float* __restrict__ forc_surf,
          const int* __restrict__ kbot,
          const float* __restrict__ dxt, const float* __restrict__ dxu,
          const float* __restrict__ dyt, const float* __restrict__ dyu,
          const float* __restrict__ dzt, const float* __restrict__ dzw,
          const float* __restrict__ cost, const float* __restrict__ cosu,
          float* __restrict__ out_tke, float* __restrict__ out_dtke,
          float* __restrict__ out_corr)
{
    const int lane = threadIdx.x;                        // k, 0..63
    const int col  = blockIdx.x * blockDim.y + threadIdx.y;
    const int i = col >> 8, j = col & (NY - 1);          // NY = 256
    const size_t SX    = (size_t)NY * NZ;
    const size_t base1 = (size_t)col * NZ;
    const size_t idx1  = base1 + lane;
    const size_t idx3  = idx1 * 3;
    const bool interior = (i >= 2 && i < NX - 2 && j >= 2 && j < NY - 2);

    const float tk_tau = tke[idx3 + 0];
    const float tk_tp1 = tke[idx3 + 1];
    const float tk_tm1 = tke[idx3 + 2];
    const float d_tp1  = dtke[idx3 + 1];
    const float d_tm1  = dtke[idx3 + 2];

    // pass-through slices
    out_tke[idx3 + 0]  = tk_tau;
    out_tke[idx3 + 2]  = tk_tm1;
    out_dtke[idx3 + 1] = d_tp1;
    out_dtke[idx3 + 2] = d_tm1;

    // ---------- tridiagonal setup (lane = row k) ----------
    const float dzwk         = dzw[lane];
    const float inv_dzwk     = rcpf(dzwk);
    const float dzw_last     = 0.5f * dzw[NZ - 1];
    const float inv_dzw_last = rcpf(dzw_last);

    float kap   = kappaM[idx1];
    float kap_p = __shfl_down(kap, 1);
    float dzt_p = dzt[(lane < NZ - 1) ? lane + 1 : NZ - 1];
    float delta = (lane < NZ - 1) ? 0.5f * (kap + kap_p) * rcpf(dzt_p) : 0.f;
    float delta_m = __shfl_up(delta, 1);
    if (lane == 0) delta_m = 0.f;

    float diss = 0.7f * sqrtf(fmaxf(0.f, tk_tau)) * rcpf(mxl[idx1]);

    float a, b;
    if (lane == 0)            { a = 0.f; b = 0.f; }
    else if (lane < NZ - 1)   { a = -delta_m * inv_dzwk;
                                b = 1.f + (delta + delta_m) * inv_dzwk + diss; }
    else                      { a = -delta_m * inv_dzw_last;
                                b = 1.f + delta_m * inv_dzw_last + diss; }
    const float b_edge = 1.f + delta * inv_dzwk + diss;
    const float c = (lane < NZ - 1) ? -delta * inv_dzwk : 0.f;
    float d = tk_tau + forc[idx1];
    if (lane == NZ - 1) d += forc_surf[col] * inv_dzw_last;

    const int  ks    = kbot[col] - 1;
    const bool land  = interior && (ks >= 0);
    const bool water = land && (lane >= ks);
    const bool edge  = land && (lane == ks);

    float A = (water && !edge) ? a : 0.f;
    float B = edge ? b_edge : (water ? b : 1.f);
    float C = water ? c : 0.f;
    float D = water ? d : 0.f;

    // ---------- parallel cyclic reduction ----------
    #pragma unroll
    for (int s = 1; s < NZ; s <<= 1) {
        float am = __shfl_up(A, s), bm = __shfl_up(B, s);
        float cm = __shfl_up(C, s), dm = __shfl_up(D, s);
        if (lane < s) { am = 0.f; bm = 1.f; cm = 0.f; dm = 0.f; }
        float ap = __shfl_down(A, s), bp = __shfl_down(B, s);
        float cq = __shfl_down(C, s), dq = __shfl_down(D, s);
        if (lane + s >= NZ) { ap = 0.f; bp = 1.f; cq = 0.f; dq = 0.f; }
        float alpha = -A * rcpf(bm);
        float beta  = -C * rcpf(bp);
        B = B + alpha * cm + beta * ap;
        D = D + alpha * dm + beta * dq;
        A = alpha * am;
        C = beta * cq;
    }
    const float x = D * rcpf(B);

    float partial = water ? x : tk_tp1;
    if (lane == NZ - 1) {
        float corr = 0.f;
        if (interior && partial < 0.f) { corr = -partial * dzw_last; partial = 0.f; }
        out_corr[col] = corr;
    }

    // ---------- diffusion + advection ----------
    float dtke_tau, diff = 0.f;
    if (interior) {
        const float cj = cost[j];

        // consolidated neighbor loads (tau slice + maskW)
        const float mw_c = maskW[idx1];
        float t_xm2 = tke[(idx1 - 2 * SX) * 3], t_xm1 = tke[(idx1 - SX) * 3];
        float t_xp1 = tke[(idx1 + SX) * 3],     t_xp2 = tke[(idx1 + 2 * SX) * 3];
        float mw_xm2 = maskW[idx1 - 2 * SX], mw_xm1 = maskW[idx1 - SX];
        float mw_xp1 = maskW[idx1 + SX],     mw_xp2 = maskW[idx1 + 2 * SX];
        float t_ym2 = tke[(idx1 - 2 * NZ) * 3], t_ym1 = tke[(idx1 - NZ) * 3];
        float t_yp1 = tke[(idx1 + NZ) * 3],     t_yp2 = tke[(idx1 + 2 * NZ) * 3];
        float mw_ym2 = maskW[idx1 - 2 * NZ], mw_ym1 = maskW[idx1 - NZ];
        float mw_yp1 = maskW[idx1 + NZ],     mw_yp2 = maskW[idx1 + 2 * NZ];

        const float rdx_i  = rcpf(cj * dxt[i]);
        const float rdx_im = rcpf(cj * dxt[i - 1]);
        const float rdy_j  = rcpf(cj * dyt[j]);
        const float rdy_jm = rcpf(cost[j - 1] * dyt[j - 1]);

        // --- x advection (two interface fluxes) ---
        float u0 = u[(idx1 - SX) * 3], u1 = u[idx3];
        float fe0 = sbflux(t_xm2, t_xm1, tk_tau, t_xp1,
                           mw_xm1 * mw_xm2, mw_c * mw_xm1, mw_xp1 * mw_c,
                           u0, 1.f, rdx_im);
        float fe1 = sbflux(t_xm1, tk_tau, t_xp1, t_xp2,
                           mw_c * mw_xm1, mw_xp1 * mw_c, mw_xp2 * mw_xp1,
                           u1, 1.f, rdx_i);

        // --- y advection ---
        float v0 = v[(idx1 - NZ) * 3], v1 = v[idx3];
        float fn0 = sbflux(t_ym2, t_ym1, tk_tau, t_yp1,
                           mw_ym1 * mw_ym2, mw_c * mw_ym1, mw_yp1 * mw_c,
                           v0, cosu[j - 1], rdy_jm);
        float fn1 = sbflux(t_ym1, tk_tau, t_yp1, t_yp2,
                           mw_c * mw_ym1, mw_yp1 * mw_c, mw_yp2 * mw_yp1,
                           v1, cosu[j], rdy_j);

        // --- z advection: all operands lane-local / shfl ---
        float mw_km1 = __shfl_up(mw_c, 1);
        float mw_kp1 = __shfl_down(mw_c, 1);
        float mw_kp2 = __shfl_down(mw_c, 2);
        float t_km1  = __shfl_up(tk_tau, 1);
        float t_kp1  = __shfl_down(tk_tau, 1);
        float t_kp2  = __shfl_down(tk_tau, 2);
        float wvel   = w[idx3];
        float mm1z = (lane >= 1) ? mw_c * mw_km1 : 0.f;
        float m0z  = mw_kp1 * mw_c;
        float mp1z = (lane + 1 < NZ - 1) ? mw_kp2 * mw_kp1 : 0.f;
        float ft = sbflux(t_km1, tk_tau, t_kp1, t_kp2,
                          mm1z, m0z, mp1z, wvel, 1.f, inv_dzwk);
        float ft_m1 = __shfl_up(ft, 1);

        float hor = mw_c * (-(fe1 - fe0) * rdx_i - (fn1 - fn0) * rdy_j);
        float vert;
        if (lane == 0)           vert = -ft * inv_dzwk;
        else if (lane < NZ - 1)  vert = -(ft - ft_m1) * inv_dzwk;
        else                     vert = ft_m1 * inv_dzw_last;
        dtke_tau = hor + vert;

        // --- horizontal diffusion (reuses neighbor loads) ---
        float fe1d = 2000.f * (t_xp1 - tk_tau) * rcpf(cj * dxu[i])     * maskU[idx1];
        float fe0d = 2000.f * (tk_tau - t_xm1) * rcpf(cj * dxu[i - 1]) * maskU[idx1 - SX];
        float fn1d = 2000.f * (t_yp1 - tk_tau) * cosu[j]     * rcpf(dyu[j])     * maskV[idx1];
        float fn0d = 2000.f * (tk_tau - t_ym1) * cosu[j - 1] * rcpf(dyu[j - 1]) * maskV[idx1 - NZ];
        diff = mw_c * ((fe1d - fe0d) * rdx_i + (fn1d - fn0d) * rdy_j);
    } else {
        dtke_tau = dtke[idx3 + 0];
    }
    out_dtke[idx3 + 0] = dtke_tau;

    // Adams-Bashforth update of taup1
    out_tke[idx3 + 1] = partial + diff + 1.6f * dtke_tau - 0.6f * d_tm1;
}

extern "C" void kernel_launch(void* const* d_in, const int* in_sizes, int n_in,
                              void* d_out, int out_size, void* d_ws, size_t ws_size,
                              hipStream_t stream)
{
    const float* u         = (const float*)d_in[0];
    const float* v         = (const float*)d_in[1];
    const float* w         = (const float*)d_in[2];
    const float* maskU     = (const float*)d_in[3];
    const float* maskV     = (const float*)d_in[4];
    const float* maskW     = (const float*)d_in[5];
    const float* dxt       = (const float*)d_in[6];
    const float* dxu       = (const float*)d_in[7];
    const float* dyt       = (const float*)d_in[8];
    const float* dyu       = (const float*)d_in[9];
    const float* dzt       = (const float*)d_in[10];
    const float* dzw       = (const float*)d_in[11];
    const float* cost      = (const float*)d_in[12];
    const float* cosu      = (const float*)d_in[13];
    const int*   kbot      = (const int*)d_in[14];
    const float* kappaM    = (const float*)d_in[15];
    const float* mxl       = (const float*)d_in[16];
    const float* forc      = (const float*)d_in[17];
    const float* forc_surf = (const float*)d_in[18];
    const float* tke       = (const float*)d_in[19];
    const float* dtke      = (const float*)d_in[20];

    float* out_tke  = (float*)d_out;
    float* out_dtke = out_tke + (size_t)NX * NY * NZ * 3;
    float* out_corr = out_dtke + (size_t)NX * NY * NZ * 3;

    tke_fused<<<dim3((NX * NY) / 4), dim3(64, 4), 0, stream>>>(
        tke, dtke, u, v, w, maskU, maskV, maskW,
        kappaM, mxl, forc, forc_surf, kbot,
        dxt, dxu, dyt, dyu, dzt, dzw, cost, cosu,
        out_tke, out_dtke, out_corr);
}

// Round 4
// 149.092 us; speedup vs baseline: 8.5739x; 1.2546x over previous
//
#include <hip/hip_runtime.h>

#define NX 352
#define NY 256
#define NZ 64

__device__ __forceinline__ float rcpf(float x) { return __builtin_amdgcn_rcpf(x); }

__device__ __forceinline__ float limiter(float cr) {
    return fmaxf(0.f, fmaxf(fminf(1.f, 2.f * cr), fminf(2.f, cr)));
}

// superbee flux; cr-switch uses raw vel sign, uCFL uses velfac*vel
__device__ __forceinline__ float sbflux(float vm1, float v0, float vp1, float vp2,
                                        float mm1, float m0, float mp1,
                                        float vel, float velfac, float rinv_dx)
{
    float rjp = (vp2 - vp1) * mp1;
    float rj  = (vp1 - v0) * m0;
    float rjm = (v0 - vm1) * mm1;
    float fv = velfac * vel;
    float uCFL = fabsf(fv * rinv_dx);
    float rden = (fabsf(rj) < 1e-20f) ? 1e-20f : rj;
    float cr = limiter(((vel > 0.f) ? rjm : rjp) * rcpf(rden));
    return fv * (vp1 + v0) * 0.5f - fabsf(fv) * ((1.f - cr) + uCFL * cr) * rj * 0.5f;
}

__global__ __launch_bounds__(256) void
tke_fused(const float* __restrict__ tke, const float* __restrict__ dtke,
          const float* __restrict__ u, const float* __restrict__ v,
          const float* __restrict__ w,
          const float* __restrict__ maskU, const float* __restrict__ maskV,
          const float* __restrict__ maskW,
          const float* __restrict__ kappaM, const float* __restrict__ mxl,
          const float* __restrict__ forc, const float* __restrict__ forc_surf,
          const int* __restrict__ kbot,
          const float* __restrict__ dxt, const float* __restrict__ dxu,
          const float* __restrict__ dyt, const float* __restrict__ dyu,
          const float* __restrict__ dzt, const float* __restrict__ dzw,
          const float* __restrict__ cost, const float* __restrict__ cosu,
          float* __restrict__ out_tke, float* __restrict__ out_dtke,
          float* __restrict__ out_corr)
{
    const int lane = threadIdx.x;                        // k, 0..63
    const int col  = blockIdx.x * blockDim.y + threadIdx.y;
    const int i = col >> 8, j = col & (NY - 1);          // NY = 256
    const size_t base1 = (size_t)col * NZ;
    const size_t idx1  = base1 + lane;
    const size_t idx3  = idx1 * 3;
    const bool interior = (i >= 2 && i < NX - 2 && j >= 2 && j < NY - 2);

    // clamped neighbor offsets: exterior waves read their own column (values unused)
    const ptrdiff_t ox = interior ? (ptrdiff_t)NY * NZ : 0;
    const ptrdiff_t oy = interior ? (ptrdiff_t)NZ : 0;
    const int im = interior ? i - 1 : i;
    const int jm = interior ? j - 1 : j;

    // ---------- vectorized column-local loads ----------
    const float3 tk3 = *reinterpret_cast<const float3*>(tke + idx3);   // tau, taup1, taum1
    const float3 dt3 = *reinterpret_cast<const float3*>(dtke + idx3);
    const float tk_tau = tk3.x;

    // ---------- stencil input loads (unconditional, clamped) ----------
    const float mw_c = maskW[idx1];
    const float t_xm2 = tke[(idx1 - 2 * ox) * 3], t_xm1 = tke[(idx1 - ox) * 3];
    const float t_xp1 = tke[(idx1 + ox) * 3],     t_xp2 = tke[(idx1 + 2 * ox) * 3];
    const float mw_xm2 = maskW[idx1 - 2 * ox], mw_xm1 = maskW[idx1 - ox];
    const float mw_xp1 = maskW[idx1 + ox],     mw_xp2 = maskW[idx1 + 2 * ox];
    const float t_ym2 = tke[(idx1 - 2 * oy) * 3], t_ym1 = tke[(idx1 - oy) * 3];
    const float t_yp1 = tke[(idx1 + oy) * 3],     t_yp2 = tke[(idx1 + 2 * oy) * 3];
    const float mw_ym2 = maskW[idx1 - 2 * oy], mw_ym1 = maskW[idx1 - oy];
    const float mw_yp1 = maskW[idx1 + oy],     mw_yp2 = maskW[idx1 + 2 * oy];
    const float u0 = u[(idx1 - ox) * 3], u1 = u[idx3];
    const float v0 = v[(idx1 - oy) * 3], v1 = v[idx3];
    const float wvel = w[idx3];
    const float mU1 = maskU[idx1], mU0 = maskU[idx1 - ox];
    const float mV1 = maskV[idx1], mV0 = maskV[idx1 - oy];

    // ---------- tridiagonal setup (lane = row k) ----------
    const float dzwk         = dzw[lane];
    const float inv_dzwk     = rcpf(dzwk);
    const float dzw_last     = 0.5f * dzw[NZ - 1];
    const float inv_dzw_last = rcpf(dzw_last);

    float kap   = kappaM[idx1];
    float kap_p = __shfl_down(kap, 1);
    float dzt_p = dzt[(lane < NZ - 1) ? lane + 1 : NZ - 1];
    float delta = (lane < NZ - 1) ? 0.5f * (kap + kap_p) * rcpf(dzt_p) : 0.f;
    float delta_m = __shfl_up(delta, 1);
    if (lane == 0) delta_m = 0.f;

    float diss = 0.7f * sqrtf(fmaxf(0.f, tk_tau)) * rcpf(mxl[idx1]);

    float a, b;
    if (lane == 0)            { a = 0.f; b = 0.f; }
    else if (lane < NZ - 1)   { a = -delta_m * inv_dzwk;
                                b = 1.f + (delta + delta_m) * inv_dzwk + diss; }
    else                      { a = -delta_m * inv_dzw_last;
                                b = 1.f + delta_m * inv_dzw_last + diss; }
    const float b_edge = 1.f + delta * inv_dzwk + diss;
    const float c = (lane < NZ - 1) ? -delta * inv_dzwk : 0.f;
    float d = tk_tau + forc[idx1];
    if (lane == NZ - 1) d += forc_surf[col] * inv_dzw_last;

    const int  ks    = kbot[col] - 1;
    const bool land  = interior && (ks >= 0);
    const bool water = land && (lane >= ks);
    const bool edge  = land && (lane == ks);

    float A = (water && !edge) ? a : 0.f;
    float B = edge ? b_edge : (water ? b : 1.f);
    float C = water ? c : 0.f;
    float D = water ? d : 0.f;

    // ---------- parallel cyclic reduction ----------
    #pragma unroll
    for (int s = 1; s < NZ; s <<= 1) {
        float am = __shfl_up(A, s), bm = __shfl_up(B, s);
        float cm = __shfl_up(C, s), dm = __shfl_up(D, s);
        if (lane < s) { am = 0.f; bm = 1.f; cm = 0.f; dm = 0.f; }
        float ap = __shfl_down(A, s), bp = __shfl_down(B, s);
        float cq = __shfl_down(C, s), dq = __shfl_down(D, s);
        if (lane + s >= NZ) { ap = 0.f; bp = 1.f; cq = 0.f; dq = 0.f; }
        float alpha = -A * rcpf(bm);
        float beta  = -C * rcpf(bp);
        B = B + alpha * cm + beta * ap;
        D = D + alpha * dm + beta * dq;
        A = alpha * am;
        C = beta * cq;
    }
    const float x = D * rcpf(B);

    float partial = water ? x : tk3.y;
    if (lane == NZ - 1) {
        float corr = 0.f;
        if (interior && partial < 0.f) { corr = -partial * dzw_last; partial = 0.f; }
        out_corr[col] = corr;
    }

    // ---------- advection + diffusion (straight-line, masked at the end) ----------
    const float cj = cost[j];
    const float rdx_i  = rcpf(cj * dxt[i]);
    const float rdx_im = rcpf(cj * dxt[im]);
    const float rdy_j  = rcpf(cj * dyt[j]);
    const float rdy_jm = rcpf(cost[jm] * dyt[jm]);

    // x advection
    float fe0 = sbflux(t_xm2, t_xm1, tk_tau, t_xp1,
                       mw_xm1 * mw_xm2, mw_c * mw_xm1, mw_xp1 * mw_c,
                       u0, 1.f, rdx_im);
    float fe1 = sbflux(t_xm1, tk_tau, t_xp1, t_xp2,
                       mw_c * mw_xm1, mw_xp1 * mw_c, mw_xp2 * mw_xp1,
                       u1, 1.f, rdx_i);
    // y advection
    float fn0 = sbflux(t_ym2, t_ym1, tk_tau, t_yp1,
                       mw_ym1 * mw_ym2, mw_c * mw_ym1, mw_yp1 * mw_c,
                       v0, cosu[jm], rdy_jm);
    float fn1 = sbflux(t_ym1, tk_tau, t_yp1, t_yp2,
                       mw_c * mw_ym1, mw_yp1 * mw_c, mw_yp2 * mw_yp1,
                       v1, cosu[j], rdy_j);
    // z advection: lane-local + shfl
    float mw_km1 = __shfl_up(mw_c, 1);
    float mw_kp1 = __shfl_down(mw_c, 1);
    float mw_kp2 = __shfl_down(mw_c, 2);
    float t_km1  = __shfl_up(tk_tau, 1);
    float t_kp1  = __shfl_down(tk_tau, 1);
    float t_kp2  = __shfl_down(tk_tau, 2);
    float mm1z = (lane >= 1) ? mw_c * mw_km1 : 0.f;
    float m0z  = mw_kp1 * mw_c;
    float mp1z = (lane + 1 < NZ - 1) ? mw_kp2 * mw_kp1 : 0.f;
    float ft = sbflux(t_km1, tk_tau, t_kp1, t_kp2,
                      mm1z, m0z, mp1z, wvel, 1.f, inv_dzwk);
    float ft_m1 = __shfl_up(ft, 1);

    float hor = mw_c * (-(fe1 - fe0) * rdx_i - (fn1 - fn0) * rdy_j);
    float vert;
    if (lane == 0)           vert = -ft * inv_dzwk;
    else if (lane < NZ - 1)  vert = -(ft - ft_m1) * inv_dzwk;
    else                     vert = ft_m1 * inv_dzw_last;

    // horizontal diffusion
    float fe1d = 2000.f * (t_xp1 - tk_tau) * rcpf(cj * dxu[i])  * mU1;
    float fe0d = 2000.f * (tk_tau - t_xm1) * rcpf(cj * dxu[im]) * mU0;
    float fn1d = 2000.f * (t_yp1 - tk_tau) * cosu[j]  * rcpf(dyu[j])  * mV1;
    float fn0d = 2000.f * (tk_tau - t_ym1) * cosu[jm] * rcpf(dyu[jm]) * mV0;
    float diff = interior ? mw_c * ((fe1d - fe0d) * rdx_i + (fn1d - fn0d) * rdy_j) : 0.f;

    const float dtke_tau = interior ? (hor + vert) : dt3.x;

    // ---------- single dense 12B store per output array ----------
    const float out_tp1 = partial + diff + 1.6f * dtke_tau - 0.6f * dt3.z;
    float3 ot; ot.x = tk3.x; ot.y = out_tp1; ot.z = tk3.z;
    *reinterpret_cast<float3*>(out_tke + idx3) = ot;
    float3 od; od.x = dtke_tau; od.y = dt3.y; od.z = dt3.z;
    *reinterpret_cast<float3*>(out_dtke + idx3) = od;
}

extern "C" void kernel_launch(void* const* d_in, const int* in_sizes, int n_in,
                              void* d_out, int out_size, void* d_ws, size_t ws_size,
                              hipStream_t stream)
{
    const float* u         = (const float*)d_in[0];
    const float* v         = (const float*)d_in[1];
    const float* w         = (const float*)d_in[2];
    const float* maskU     = (const float*)d_in[3];
    const float* maskV     = (const float*)d_in[4];
    const float* maskW     = (const float*)d_in[5];
    const float* dxt       = (const float*)d_in[6];
    const float* dxu       = (const float*)d_in[7];
    const float* dyt       = (const float*)d_in[8];
    const float* dyu       = (const float*)d_in[9];
    const float* dzt       = (const float*)d_in[10];
    const float* dzw       = (const float*)d_in[11];
    const float* cost      = (const float*)d_in[12];
    const float* cosu      = (const float*)d_in[13];
    const int*   kbot      = (const int*)d_in[14];
    const float* kappaM    = (const float*)d_in[15];
    const float* mxl       = (const float*)d_in[16];
    const float* forc      = (const float*)d_in[17];
    const float* forc_surf = (const float*)d_in[18];
    const float* tke       = (const float*)d_in[19];
    const float* dtke      = (const float*)d_in[20];

    float* out_tke  = (float*)d_out;
    float* out_dtke = out_tke + (size_t)NX * NY * NZ * 3;
    float* out_corr = out_dtke + (size_t)NX * NY * NZ * 3;

    tke_fused<<<dim3((NX * NY) / 4), dim3(64, 4), 0, stream>>>(
        tke, dtke, u, v, w, maskU, maskV, maskW,
        kappaM, mxl, forc, forc_surf, kbot,
        dxt, dxu, dyt, dyu, dzt, dzw, cost, cosu,
        out_tke, out_dtke, out_corr);
}

// Round 5
// 130.878 us; speedup vs baseline: 9.7671x; 1.1392x over previous
//
#include <hip/hip_runtime.h>

#define NX 352
#define NY 256
#define NZ 64

__device__ __forceinline__ float rcpf(float x) { return __builtin_amdgcn_rcpf(x); }

__device__ __forceinline__ float limiter(float cr) {
    return fmaxf(0.f, fmaxf(fminf(1.f, 2.f * cr), fminf(2.f, cr)));
}

// superbee flux; cr-switch uses raw vel sign, uCFL uses velfac*vel
__device__ __forceinline__ float sbflux(float vm1, float v0, float vp1, float vp2,
                                        float mm1, float m0, float mp1,
                                        float vel, float velfac, float rinv_dx)
{
    float rjp = (vp2 - vp1) * mp1;
    float rj  = (vp1 - v0) * m0;
    float rjm = (v0 - vm1) * mm1;
    float fv = velfac * vel;
    float uCFL = fabsf(fv * rinv_dx);
    float rden = (fabsf(rj) < 1e-20f) ? 1e-20f : rj;
    float cr = limiter(((vel > 0.f) ? rjm : rjp) * rcpf(rden));
    return fv * (vp1 + v0) * 0.5f - fabsf(fv) * ((1.f - cr) + uCFL * cr) * rj * 0.5f;
}

__global__ __launch_bounds__(256) void
tke_fused(const float* __restrict__ tke, const float* __restrict__ dtke,
          const float* __restrict__ u, const float* __restrict__ v,
          const float* __restrict__ w,
          const float* __restrict__ maskU, const float* __restrict__ maskV,
          const float* __restrict__ maskW,
          const float* __restrict__ kappaM, const float* __restrict__ mxl,
          const float* __restrict__ forc, const float* __restrict__ forc_surf,
          const int* __restrict__ kbot,
          const float* __restrict__ dxt, const float* __restrict__ dxu,
          const float* __restrict__ dyt, const float* __restrict__ dyu,
          const float* __restrict__ dzt, const float* __restrict__ dzw,
          const float* __restrict__ cost, const float* __restrict__ cosu,
          float* __restrict__ out_tke, float* __restrict__ out_dtke,
          float* __restrict__ out_corr)
{
    const int lane = threadIdx.x;                    // k, 0..63
    const int pr   = blockIdx.x * 4 + threadIdx.y;   // pair id over (NX/2, NY)
    const int ip = pr >> 8;                          // NY = 256
    const int j  = pr & 255;
    const int i0 = ip << 1;                          // even; pair (i0, i0+1)
    // i0 even => both columns interior or both exterior
    const bool interior = (i0 >= 2 && i0 < NX - 2 && j >= 2 && j < NY - 2);

    const unsigned SX = (unsigned)NY * NZ;
    const unsigned colA = (unsigned)i0 * NY + j;
    const unsigned colB = colA + NY;
    const unsigned a1 = colA * NZ + lane;
    const unsigned b1 = a1 + SX;
    const unsigned a3 = 3u * a1, b3 = 3u * b1;

    const unsigned ox = interior ? SX : 0u;
    const unsigned oy = interior ? (unsigned)NZ : 0u;
    const int imA = interior ? i0 - 1 : i0;
    const int jm  = interior ? j - 1 : j;

    // ---------- vector column loads ----------
    const float3 tkA = *reinterpret_cast<const float3*>(tke + a3);
    const float3 tkB = *reinterpret_cast<const float3*>(tke + b3);
    const float3 dtA = *reinterpret_cast<const float3*>(dtke + a3);
    const float3 dtB = *reinterpret_cast<const float3*>(dtke + b3);

    // ---------- shared x-plane stencil loads ----------
    const float t_m2 = tke[(a1 - 2u * ox) * 3], t_m1 = tke[(a1 - ox) * 3];
    const float t_p2 = tke[(b1 + ox) * 3],      t_p3 = tke[(b1 + 2u * ox) * 3];
    const float mw_m2 = maskW[a1 - 2u * ox], mw_m1 = maskW[a1 - ox];
    const float mwA = maskW[a1], mwB = maskW[b1];
    const float mw_p2 = maskW[b1 + ox], mw_p3 = maskW[b1 + 2u * ox];

    // ---------- per-column y-plane loads ----------
    const float tA_ym2 = tke[(a1 - 2u * oy) * 3], tA_ym1 = tke[(a1 - oy) * 3];
    const float tA_yp1 = tke[(a1 + oy) * 3],      tA_yp2 = tke[(a1 + 2u * oy) * 3];
    const float tB_ym2 = tke[(b1 - 2u * oy) * 3], tB_ym1 = tke[(b1 - oy) * 3];
    const float tB_yp1 = tke[(b1 + oy) * 3],      tB_yp2 = tke[(b1 + 2u * oy) * 3];
    const float mwA_ym2 = maskW[a1 - 2u * oy], mwA_ym1 = maskW[a1 - oy];
    const float mwA_yp1 = maskW[a1 + oy],      mwA_yp2 = maskW[a1 + 2u * oy];
    const float mwB_ym2 = maskW[b1 - 2u * oy], mwB_ym1 = maskW[b1 - oy];
    const float mwB_yp1 = maskW[b1 + oy],      mwB_yp2 = maskW[b1 + 2u * oy];

    // velocities + face masks
    const float uA0 = u[(a1 - ox) * 3], uA1 = u[a3], uB1 = u[b3];
    const float vA0 = v[(a1 - oy) * 3], vA1 = v[a3];
    const float vB0 = v[(b1 - oy) * 3], vB1 = v[b3];
    const float wA = w[a3], wB = w[b3];
    const float mUA0 = maskU[a1 - ox], mUA1 = maskU[a1], mUB1 = maskU[b1];
    const float mVA0 = maskV[a1 - oy], mVA1 = maskV[a1];
    const float mVB0 = maskV[b1 - oy], mVB1 = maskV[b1];

    // tridiag inputs
    const float kapA = kappaM[a1], kapB = kappaM[b1];
    const float mxA = mxl[a1], mxB = mxl[b1];
    const float foA = forc[a1], foB = forc[b1];
    const int   ksA = kbot[colA] - 1, ksB = kbot[colB] - 1;
    const float fsA = forc_surf[colA], fsB = forc_surf[colB];

    // lane constants
    const float dzwk         = dzw[lane];
    const float inv_dzwk     = rcpf(dzwk);
    const float dzw_last     = 0.5f * dzw[NZ - 1];
    const float inv_dzw_last = rcpf(dzw_last);
    const float inv_dzt_p    = rcpf(dzt[(lane < NZ - 1) ? lane + 1 : NZ - 1]);

    // ---------- tridiag setup + row-normalize (b -> 1) ----------
    bool waterA, waterB;
    float A0, C0, D0, A1c, C1c, D1c;
    {
        float kp = __shfl_down(kapA, 1);
        float delta = (lane < NZ - 1) ? 0.5f * (kapA + kp) * inv_dzt_p : 0.f;
        float dm = __shfl_up(delta, 1); if (lane == 0) dm = 0.f;
        float diss = 0.7f * sqrtf(fmaxf(0.f, tkA.x)) * rcpf(mxA);
        float a, b;
        if (lane == 0)          { a = 0.f; b = 0.f; }
        else if (lane < NZ - 1) { a = -dm * inv_dzwk; b = 1.f + (delta + dm) * inv_dzwk + diss; }
        else                    { a = -dm * inv_dzw_last; b = 1.f + dm * inv_dzw_last + diss; }
        float bE = 1.f + delta * inv_dzwk + diss;
        float c  = (lane < NZ - 1) ? -delta * inv_dzwk : 0.f;
        float d  = tkA.x + foA;
        if (lane == NZ - 1) d += fsA * inv_dzw_last;
        bool land = interior && (ksA >= 0);
        waterA = land && (lane >= ksA);
        bool edge = land && (lane == ksA);
        float A = (waterA && !edge) ? a : 0.f;
        float B = edge ? bE : (waterA ? b : 1.f);
        float C = waterA ? c : 0.f;
        float D = waterA ? d : 0.f;
        float r = rcpf(B);
        A0 = A * r; C0 = C * r; D0 = D * r;
    }
    {
        float kp = __shfl_down(kapB, 1);
        float delta = (lane < NZ - 1) ? 0.5f * (kapB + kp) * inv_dzt_p : 0.f;
        float dm = __shfl_up(delta, 1); if (lane == 0) dm = 0.f;
        float diss = 0.7f * sqrtf(fmaxf(0.f, tkB.x)) * rcpf(mxB);
        float a, b;
        if (lane == 0)          { a = 0.f; b = 0.f; }
        else if (lane < NZ - 1) { a = -dm * inv_dzwk; b = 1.f + (delta + dm) * inv_dzwk + diss; }
        else                    { a = -dm * inv_dzw_last; b = 1.f + dm * inv_dzw_last + diss; }
        float bE = 1.f + delta * inv_dzwk + diss;
        float c  = (lane < NZ - 1) ? -delta * inv_dzwk : 0.f;
        float d  = tkB.x + foB;
        if (lane == NZ - 1) d += fsB * inv_dzw_last;
        bool land = interior && (ksB >= 0);
        waterB = land && (lane >= ksB);
        bool edge = land && (lane == ksB);
        float A = (waterB && !edge) ? a : 0.f;
        float B = edge ? bE : (waterB ? b : 1.f);
        float C = waterB ? c : 0.f;
        float D = waterB ? d : 0.f;
        float r = rcpf(B);
        A1c = A * r; C1c = C * r; D1c = D * r;
    }

    // ---------- normalized PCR, two interleaved chains ----------
    #pragma unroll
    for (int s = 1; s < NZ; s <<= 1) {
        const bool lo = (lane < s);
        const bool hi = (lane + s >= NZ);
        float am0 = __shfl_up(A0, s),  cm0 = __shfl_up(C0, s),  dm0 = __shfl_up(D0, s);
        float am1 = __shfl_up(A1c, s), cm1 = __shfl_up(C1c, s), dm1 = __shfl_up(D1c, s);
        float ap0 = __shfl_down(A0, s),  cp0 = __shfl_down(C0, s),  dp0 = __shfl_down(D0, s);
        float ap1 = __shfl_down(A1c, s), cp1 = __shfl_down(C1c, s), dp1 = __shfl_down(D1c, s);
        if (lo) { am0 = 0.f; cm0 = 0.f; dm0 = 0.f; am1 = 0.f; cm1 = 0.f; dm1 = 0.f; }
        if (hi) { ap0 = 0.f; cp0 = 0.f; dp0 = 0.f; ap1 = 0.f; cp1 = 0.f; dp1 = 0.f; }
        float r0 = rcpf(1.f - A0 * cm0 - C0 * ap0);
        float r1 = rcpf(1.f - A1c * cm1 - C1c * ap1);
        float nA0 = -A0 * am0 * r0,  nC0 = -C0 * cp0 * r0;
        float nD0 = (D0 - A0 * dm0 - C0 * dp0) * r0;
        float nA1 = -A1c * am1 * r1, nC1 = -C1c * cp1 * r1;
        float nD1 = (D1c - A1c * dm1 - C1c * dp1) * r1;
        A0 = nA0; C0 = nC0; D0 = nD0;
        A1c = nA1; C1c = nC1; D1c = nD1;
    }

    float partialA = waterA ? D0 : tkA.y;
    float partialB = waterB ? D1c : tkB.y;
    if (lane == NZ - 1) {
        float corrA = 0.f, corrB = 0.f;
        if (interior && partialA < 0.f) { corrA = -partialA * dzw_last; partialA = 0.f; }
        if (interior && partialB < 0.f) { corrB = -partialB * dzw_last; partialB = 0.f; }
        out_corr[colA] = corrA;
        out_corr[colB] = corrB;
    }

    // ---------- geometry factors ----------
    const float cj = cost[j];
    const float rdx_m = rcpf(cj * dxt[imA]);        // interface i0-1
    const float rdx_0 = rcpf(cj * dxt[i0]);         // interface i0 / col A divisor
    const float rdx_1 = rcpf(cj * dxt[i0 + 1]);     // interface i0+1 / col B divisor
    const float rdy_j  = rcpf(cj * dyt[j]);
    const float rdy_jm = rcpf(cost[jm] * dyt[jm]);
    const float cu_j = cosu[j], cu_jm = cosu[jm];
    const float cud_j  = cu_j * rcpf(dyu[j]);
    const float cud_jm = cu_jm * rcpf(dyu[jm]);
    const float rdxu_m = rcpf(cj * dxu[imA]);
    const float rdxu_0 = rcpf(cj * dxu[i0]);
    const float rdxu_1 = rcpf(cj * dxu[i0 + 1]);

    // ---------- x advection: 3 interface fluxes (middle shared) ----------
    const float mxf_m1 = mwA * mw_m1;   // maskUtr at i0-1
    const float mxf_0  = mwB * mwA;     // maskUtr at i0
    const float mxf_p1 = mw_p2 * mwB;   // maskUtr at i0+1
    float feA0 = sbflux(t_m2, t_m1, tkA.x, tkB.x,
                        mw_m1 * mw_m2, mxf_m1, mxf_0, uA0, 1.f, rdx_m);
    float feI  = sbflux(t_m1, tkA.x, tkB.x, t_p2,
                        mxf_m1, mxf_0, mxf_p1, uA1, 1.f, rdx_0);
    float feB1 = sbflux(tkA.x, tkB.x, t_p2, t_p3,
                        mxf_0, mxf_p1, mw_p3 * mw_p2, uB1, 1.f, rdx_1);

    // ---------- y advection per column ----------
    float fnA0 = sbflux(tA_ym2, tA_ym1, tkA.x, tA_yp1,
                        mwA_ym1 * mwA_ym2, mwA * mwA_ym1, mwA_yp1 * mwA,
                        vA0, cu_jm, rdy_jm);
    float fnA1 = sbflux(tA_ym1, tkA.x, tA_yp1, tA_yp2,
                        mwA * mwA_ym1, mwA_yp1 * mwA, mwA_yp2 * mwA_yp1,
                        vA1, cu_j, rdy_j);
    float fnB0 = sbflux(tB_ym2, tB_ym1, tkB.x, tB_yp1,
                        mwB_ym1 * mwB_ym2, mwB * mwB_ym1, mwB_yp1 * mwB,
                        vB0, cu_jm, rdy_jm);
    float fnB1 = sbflux(tB_ym1, tkB.x, tB_yp1, tB_yp2,
                        mwB * mwB_ym1, mwB_yp1 * mwB, mwB_yp2 * mwB_yp1,
                        vB1, cu_j, rdy_j);

    // ---------- z advection per column (lane-local + shfl) ----------
    float mwA_km1 = __shfl_up(mwA, 1),  mwA_kp1 = __shfl_down(mwA, 1),  mwA_kp2 = __shfl_down(mwA, 2);
    float mwB_km1 = __shfl_up(mwB, 1),  mwB_kp1 = __shfl_down(mwB, 1),  mwB_kp2 = __shfl_down(mwB, 2);
    float tA_km1 = __shfl_up(tkA.x, 1), tA_kp1 = __shfl_down(tkA.x, 1), tA_kp2 = __shfl_down(tkA.x, 2);
    float tB_km1 = __shfl_up(tkB.x, 1), tB_kp1 = __shfl_down(tkB.x, 1), tB_kp2 = __shfl_down(tkB.x, 2);
    float mm1zA = (lane >= 1) ? mwA * mwA_km1 : 0.f;
    float m0zA  = mwA_kp1 * mwA;
    float mp1zA = (lane + 1 < NZ - 1) ? mwA_kp2 * mwA_kp1 : 0.f;
    float mm1zB = (lane >= 1) ? mwB * mwB_km1 : 0.f;
    float m0zB  = mwB_kp1 * mwB;
    float mp1zB = (lane + 1 < NZ - 1) ? mwB_kp2 * mwB_kp1 : 0.f;
    float ftA = sbflux(tA_km1, tkA.x, tA_kp1, tA_kp2, mm1zA, m0zA, mp1zA, wA, 1.f, inv_dzwk);
    float ftB = sbflux(tB_km1, tkB.x, tB_kp1, tB_kp2, mm1zB, m0zB, mp1zB, wB, 1.f, inv_dzwk);
    float ftA_m1 = __shfl_up(ftA, 1);
    float ftB_m1 = __shfl_up(ftB, 1);

    float vertA, vertB;
    if (lane == 0)           { vertA = -ftA * inv_dzwk;            vertB = -ftB * inv_dzwk; }
    else if (lane < NZ - 1)  { vertA = -(ftA - ftA_m1) * inv_dzwk; vertB = -(ftB - ftB_m1) * inv_dzwk; }
    else                     { vertA = ftA_m1 * inv_dzw_last;      vertB = ftB_m1 * inv_dzw_last; }

    float horA = mwA * (-(feI - feA0) * rdx_0 - (fnA1 - fnA0) * rdy_j);
    float horB = mwB * (-(feB1 - feI) * rdx_1 - (fnB1 - fnB0) * rdy_j);

    // ---------- horizontal diffusion: 3 x-face fluxes (middle shared) ----------
    float feDm = 2000.f * (tkA.x - t_m1)  * rdxu_m * mUA0;
    float feD0 = 2000.f * (tkB.x - tkA.x) * rdxu_0 * mUA1;
    float feDp = 2000.f * (t_p2 - tkB.x)  * rdxu_1 * mUB1;
    float fnD1A = 2000.f * (tA_yp1 - tkA.x) * cud_j  * mVA1;
    float fnD0A = 2000.f * (tkA.x - tA_ym1) * cud_jm * mVA0;
    float fnD1B = 2000.f * (tB_yp1 - tkB.x) * cud_j  * mVB1;
    float fnD0B = 2000.f * (tkB.x - tB_ym1) * cud_jm * mVB0;
    float diffA = interior ? mwA * ((feD0 - feDm) * rdx_0 + (fnD1A - fnD0A) * rdy_j) : 0.f;
    float diffB = interior ? mwB * ((feDp - feD0) * rdx_1 + (fnD1B - fnD0B) * rdy_j) : 0.f;

    const float dtkeA = interior ? (horA + vertA) : dtA.x;
    const float dtkeB = interior ? (horB + vertB) : dtB.x;

    // ---------- dense 12B stores ----------
    float3 otA; otA.x = tkA.x; otA.y = partialA + diffA + 1.6f * dtkeA - 0.6f * dtA.z; otA.z = tkA.z;
    float3 otB; otB.x = tkB.x; otB.y = partialB + diffB + 1.6f * dtkeB - 0.6f * dtB.z; otB.z = tkB.z;
    *reinterpret_cast<float3*>(out_tke + a3) = otA;
    *reinterpret_cast<float3*>(out_tke + b3) = otB;
    float3 odA; odA.x = dtkeA; odA.y = dtA.y; odA.z = dtA.z;
    float3 odB; odB.x = dtkeB; odB.y = dtB.y; odB.z = dtB.z;
    *reinterpret_cast<float3*>(out_dtke + a3) = odA;
    *reinterpret_cast<float3*>(out_dtke + b3) = odB;
}

extern "C" void kernel_launch(void* const* d_in, const int* in_sizes, int n_in,
                              void* d_out, int out_size, void* d_ws, size_t ws_size,
                              hipStream_t stream)
{
    const float* u         = (const float*)d_in[0];
    const float* v         = (const float*)d_in[1];
    const float* w         = (const float*)d_in[2];
    const float* maskU     = (const float*)d_in[3];
    const float* maskV     = (const float*)d_in[4];
    const float* maskW     = (const float*)d_in[5];
    const float* dxt       = (const float*)d_in[6];
    const float* dxu       = (const float*)d_in[7];
    const float* dyt       = (const float*)d_in[8];
    const float* dyu       = (const float*)d_in[9];
    const float* dzt       = (const float*)d_in[10];
    const float* dzw       = (const float*)d_in[11];
    const float* cost      = (const float*)d_in[12];
    const float* cosu      = (const float*)d_in[13];
    const int*   kbot      = (const int*)d_in[14];
    const float* kappaM    = (const float*)d_in[15];
    const float* mxl       = (const float*)d_in[16];
    const float* forc      = (const float*)d_in[17];
    const float* forc_surf = (const float*)d_in[18];
    const float* tke       = (const float*)d_in[19];
    const float* dtke      = (const float*)d_in[20];

    float* out_tke  = (float*)d_out;
    float* out_dtke = out_tke + (size_t)NX * NY * NZ * 3;
    float* out_corr = out_dtke + (size_t)NX * NY * NZ * 3;

    // (NX/2) * NY column pairs, 4 pairs per block
    tke_fused<<<dim3((NX / 2) * NY / 4), dim3(64, 4), 0, stream>>>(
        tke, dtke, u, v, w, maskU, maskV, maskW,
        kappaM, mxl, forc, forc_surf, kbot,
        dxt, dxu, dyt, dyu, dzt, dzw, cost, cosu,
        out_tke, out_dtke, out_corr);
}